// Round 1
// baseline (271.346 us; speedup 1.0000x reference)
//
#include <hip/hip_runtime.h>
#include <stdint.h>

#define NROW 2048
#define D_IM 1024
#define D_CLI 64
#define EPSF 1e-12f
#define NN ((size_t)NROW * (size_t)NROW)

// ws layout:
//   [0,48)            : unsigned long long packed[6]  (argmin slots)
//   [64, 64+8192)     : float inv_im[2048]
//   [8256, +8192)     : float inv_cli[2048]
//   [16448, +8192)    : int cat[2048]

// Order-preserving float->uint encode: a < b  <=>  enc(a) < enc(b)
__device__ __forceinline__ unsigned int enc_f32(float x) {
    unsigned int u = __float_as_uint(x);
    return (u & 0x80000000u) ? ~u : (u | 0x80000000u);
}

__global__ void prep_kernel(const float* __restrict__ phi_im,
                            const float* __restrict__ phi_cli,
                            const int* __restrict__ t,
                            const int* __restrict__ traumatic,
                            float* __restrict__ inv_im,
                            float* __restrict__ inv_cli,
                            int* __restrict__ cat,
                            unsigned long long* __restrict__ packed) {
    __shared__ float sred[256];
    const int r = blockIdx.x;
    const int tid = threadIdx.x;

    // im row: 1024 floats = 256 float4, one per thread
    float4 v = ((const float4*)(phi_im + (size_t)r * D_IM))[tid];
    sred[tid] = v.x * v.x + v.y * v.y + v.z * v.z + v.w * v.w;
    __syncthreads();
    for (int off = 128; off > 0; off >>= 1) {
        if (tid < off) sred[tid] += sred[tid + off];
        __syncthreads();
    }

    // cli row: 64 floats, wave 0 shuffle-reduce
    if (tid < 64) {
        float c = phi_cli[(size_t)r * D_CLI + tid];
        float cs = c * c;
        #pragma unroll
        for (int off = 32; off > 0; off >>= 1) cs += __shfl_down(cs, off, 64);
        if (tid == 0) inv_cli[r] = 1.0f / fmaxf(sqrtf(cs), EPSF);
    }

    if (tid == 0) {
        inv_im[r] = 1.0f / fmaxf(sqrtf(sred[0]), EPSF);
        int t1 = t[2 * r + 1];
        int tr = traumatic[r];
        // category: 0 = m0 ((t1==0)&(tr==1)), 1 = m1, 2 = m2, 3 = none
        cat[r] = (t1 == 1) ? 1 : ((t1 == 2) ? 2 : ((tr == 1) ? 0 : 3));
    }
    if (r == 0 && tid < 6) packed[tid] = 0xFFFFFFFFFFFFFFFFULL;
}

#define BLK 128
#define BK 16

__global__ __launch_bounds__(256)
void gemm_kernel(const float* __restrict__ phi_im,
                 const float* __restrict__ phi_cli,
                 const float* __restrict__ inv_im,
                 const float* __restrict__ inv_cli,
                 const int* __restrict__ cat,
                 float* __restrict__ out,
                 unsigned long long* __restrict__ packed) {
    __shared__ float As[BK][BLK + 4];   // k-major, pad 4: write aliasing is 2-way (free)
    __shared__ float Bs[BK][BLK + 4];
    __shared__ unsigned long long red[256];

    const int z = blockIdx.z;
    const float* __restrict__ X = (z == 0) ? phi_im : phi_cli;
    const float* __restrict__ inv = (z == 0) ? inv_im : inv_cli;
    const int K = (z == 0) ? D_IM : D_CLI;

    const int i0 = blockIdx.y * BLK;
    const int j0 = blockIdx.x * BLK;
    const int tid = threadIdx.x;
    const int tx = tid & 15;   // 16 col-groups
    const int ty = tid >> 4;   // 16 row-groups

    float acc[8][8];
    #pragma unroll
    for (int r = 0; r < 8; r++)
        #pragma unroll
        for (int c = 0; c < 8; c++) acc[r][c] = 0.0f;

    for (int kk = 0; kk < K; kk += BK) {
        // stage 128x16 A-tile and B-tile (both are rows of X): 512 float4 loads
        #pragma unroll
        for (int l = 0; l < 2; l++) {
            int idx = tid + l * 256;         // 0..511
            int row = idx >> 2;              // 0..127
            int kp  = (idx & 3) << 2;        // 0,4,8,12
            float4 av = *(const float4*)(X + (size_t)(i0 + row) * K + kk + kp);
            As[kp + 0][row] = av.x; As[kp + 1][row] = av.y;
            As[kp + 2][row] = av.z; As[kp + 3][row] = av.w;
            float4 bv = *(const float4*)(X + (size_t)(j0 + row) * K + kk + kp);
            Bs[kp + 0][row] = bv.x; Bs[kp + 1][row] = bv.y;
            Bs[kp + 2][row] = bv.z; Bs[kp + 3][row] = bv.w;
        }
        __syncthreads();

        #pragma unroll
        for (int k = 0; k < BK; k++) {
            // fragment = 4 rows at ty*4 plus 4 rows at 64+ty*4 (stride-64 split
            // keeps the 16 distinct B b128 reads 2-way bank-aliased = free)
            float a[8], b[8];
            float4 a0 = *(const float4*)&As[k][ty * 4];
            float4 a1 = *(const float4*)&As[k][64 + ty * 4];
            float4 b0 = *(const float4*)&Bs[k][tx * 4];
            float4 b1 = *(const float4*)&Bs[k][64 + tx * 4];
            a[0] = a0.x; a[1] = a0.y; a[2] = a0.z; a[3] = a0.w;
            a[4] = a1.x; a[5] = a1.y; a[6] = a1.z; a[7] = a1.w;
            b[0] = b0.x; b[1] = b0.y; b[2] = b0.z; b[3] = b0.w;
            b[4] = b1.x; b[5] = b1.y; b[6] = b1.z; b[7] = b1.w;
            #pragma unroll
            for (int r = 0; r < 8; r++)
                #pragma unroll
                for (int c = 0; c < 8; c++)
                    acc[r][c] = fmaf(a[r], b[c], acc[r][c]);
        }
        __syncthreads();
    }

    // ---- epilogue: scale, mask, store 3 matrices, argmin-reduce ----
    int rI[8], cI[8], catR[8], catC[8];
    float invR[8], invC[8];
    #pragma unroll
    for (int h = 0; h < 2; h++)
        #pragma unroll
        for (int q = 0; q < 4; q++) {
            int e = h * 4 + q;
            rI[e] = i0 + h * 64 + ty * 4 + q;
            cI[e] = j0 + h * 64 + tx * 4 + q;
        }
    #pragma unroll
    for (int e = 0; e < 8; e++) {
        invR[e] = inv[rI[e]]; catR[e] = cat[rI[e]];
        invC[e] = inv[cI[e]]; catC[e] = cat[cI[e]];
    }

    unsigned long long best[3] = {~0ULL, ~0ULL, ~0ULL};
    const size_t matbase = (size_t)z * 3 * NN;

    #pragma unroll
    for (int r = 0; r < 8; r++) {
        float sv[8];
        #pragma unroll
        for (int c = 0; c < 8; c++) sv[c] = acc[r][c] * (invR[r] * invC[c]);
        const size_t rowoff = matbase + (size_t)rI[r] * NROW;
        #pragma unroll
        for (int p = 0; p < 3; p++) {
            const int pa = (p == 2) ? 1 : 0;          // row mask: m0,m0,m1
            const int pb = (p == 0) ? 1 : 2;          // col mask: m1,m2,m2
            float* op = out + (size_t)p * NN + rowoff;
            float vv[8];
            if (catR[r] == pa) {
                #pragma unroll
                for (int c = 0; c < 8; c++) {
                    bool valid = (catC[c] == pb);
                    vv[c] = valid ? sv[c] : 0.0f;
                    if (valid) {
                        unsigned long long pk =
                            ((unsigned long long)enc_f32(sv[c]) << 32) |
                            (unsigned int)(rI[r] * NROW + cI[c]);
                        if (pk < best[p]) best[p] = pk;
                    }
                }
            } else {
                #pragma unroll
                for (int c = 0; c < 8; c++) vv[c] = 0.0f;
            }
            *(float4*)(op + cI[0]) = make_float4(vv[0], vv[1], vv[2], vv[3]);
            *(float4*)(op + cI[4]) = make_float4(vv[4], vv[5], vv[6], vv[7]);
        }
    }

    // block-level argmin reduce, then one atomic per pair
    #pragma unroll 1
    for (int p = 0; p < 3; p++) {
        red[tid] = best[p];
        __syncthreads();
        for (int off = 128; off > 0; off >>= 1) {
            if (tid < off) {
                if (red[tid + off] < red[tid]) red[tid] = red[tid + off];
            }
            __syncthreads();
        }
        if (tid == 0 && red[0] != ~0ULL) atomicMin(&packed[z * 3 + p], red[0]);
        __syncthreads();
    }
}

__global__ void finalize_kernel(const unsigned long long* __restrict__ packed,
                                float* __restrict__ out) {
    int p = threadIdx.x;
    if (p < 6) {
        unsigned long long pk = packed[p];
        float v;
        unsigned int flat;
        if (pk == 0xFFFFFFFFFFFFFFFFULL) {   // no valid pair: argmin of all-inf
            v = __builtin_huge_valf();
            flat = 0u;
        } else {
            unsigned int key = (unsigned int)(pk >> 32);
            flat = (unsigned int)pk;
            unsigned int bits = (key & 0x80000000u) ? (key ^ 0x80000000u) : ~key;
            v = __uint_as_float(bits);
        }
        float* mv = out + 6 * NN;
        mv[p] = v;
        float* mi = out + 6 * NN + 6;
        mi[2 * p + 0] = (float)(flat >> 11);     // i = flat / 2048
        mi[2 * p + 1] = (float)(flat & 2047u);   // j = flat % 2048
    }
}

extern "C" void kernel_launch(void* const* d_in, const int* in_sizes, int n_in,
                              void* d_out, int out_size, void* d_ws, size_t ws_size,
                              hipStream_t stream) {
    const float* phi_im = (const float*)d_in[0];
    const float* phi_cli = (const float*)d_in[1];
    const int* t = (const int*)d_in[2];
    const int* traumatic = (const int*)d_in[3];
    float* out = (float*)d_out;

    char* ws = (char*)d_ws;
    unsigned long long* packed = (unsigned long long*)ws;
    float* inv_im = (float*)(ws + 64);
    float* inv_cli = (float*)(ws + 64 + 8192);
    int* cat = (int*)(ws + 64 + 16384);

    prep_kernel<<<NROW, 256, 0, stream>>>(phi_im, phi_cli, t, traumatic,
                                          inv_im, inv_cli, cat, packed);
    dim3 grid(NROW / BLK, NROW / BLK, 2);
    gemm_kernel<<<grid, 256, 0, stream>>>(phi_im, phi_cli, inv_im, inv_cli,
                                          cat, out, packed);
    finalize_kernel<<<1, 64, 0, stream>>>(packed, out);
}

// Round 2
// 229.495 us; speedup vs baseline: 1.1824x; 1.1824x over previous
//
#include <hip/hip_runtime.h>
#include <stdint.h>

#define NROW 2048
#define D_IM 1024
#define D_CLI 64
#define EPSF 1e-12f
#define NN ((size_t)NROW * (size_t)NROW)

// ws layout:
//   [0,48)      u64 packed[6]        argmin slots
//   [64,80)     int cnt[4]           per-category row counts (3 used + spill)
//   [128,24704) int lists[3][2048]   row indices per category
//   [24704,+8K) float inv_im[2048]
//   [32896,+8K) float inv_cli[2048]

__device__ __forceinline__ unsigned int enc_f32(float x) {
    unsigned int u = __float_as_uint(x);
    return (u & 0x80000000u) ? ~u : (u | 0x80000000u);
}

__global__ void init_kernel(unsigned long long* __restrict__ packed,
                            int* __restrict__ cnt) {
    int t = threadIdx.x;
    if (t < 6) packed[t] = 0xFFFFFFFFFFFFFFFFULL;
    if (t < 4) cnt[t] = 0;
}

// One block per row: row norms, category list build, plus a slice of the
// output zero-fill (6*NN floats = 1,572,864 float4 = 2048 blocks * 256 thr * 3).
__global__ void prep_kernel(const float* __restrict__ phi_im,
                            const float* __restrict__ phi_cli,
                            const int* __restrict__ t,
                            const int* __restrict__ traumatic,
                            float* __restrict__ inv_im,
                            float* __restrict__ inv_cli,
                            int* __restrict__ cnt,
                            int* __restrict__ lists,
                            float* __restrict__ out) {
    __shared__ float sred[256];
    const int r = blockIdx.x;
    const int tid = threadIdx.x;

    // zero-fill slice (coalesced float4)
    float4* out4 = (float4*)out;
    const int gid = blockIdx.x * 256 + tid;
    const float4 z4 = make_float4(0.f, 0.f, 0.f, 0.f);
    out4[gid] = z4;
    out4[gid + 524288] = z4;
    out4[gid + 1048576] = z4;

    // im row norm: 1024 floats = 256 float4
    float4 v = ((const float4*)(phi_im + (size_t)r * D_IM))[tid];
    sred[tid] = v.x * v.x + v.y * v.y + v.z * v.z + v.w * v.w;
    __syncthreads();
    for (int off = 128; off > 0; off >>= 1) {
        if (tid < off) sred[tid] += sred[tid + off];
        __syncthreads();
    }

    // cli row norm: 64 floats, wave 0
    if (tid < 64) {
        float c = phi_cli[(size_t)r * D_CLI + tid];
        float cs = c * c;
        #pragma unroll
        for (int off = 32; off > 0; off >>= 1) cs += __shfl_down(cs, off, 64);
        if (tid == 0) inv_cli[r] = 1.0f / fmaxf(sqrtf(cs), EPSF);
    }

    if (tid == 0) {
        inv_im[r] = 1.0f / fmaxf(sqrtf(sred[0]), EPSF);
        int t1 = t[2 * r + 1];
        int tr = traumatic[r];
        // 0 = m0 ((t1==0)&(tr==1)), 1 = m1, 2 = m2, 3 = none
        int cat = (t1 == 1) ? 1 : ((t1 == 2) ? 2 : ((tr == 1) ? 0 : 3));
        if (cat < 3) {
            int slot = atomicAdd(&cnt[cat], 1);
            lists[cat * 2048 + slot] = r;
        }
    }
}

// Compact gather-GEMM: single-wave blocks, 32x32 tile, 4x4 micro, BK=32.
// LDS row-major with XOR swizzle on 16B chunks: writes 2-way (free),
// fragment reads conflict-free b128 with 8-way broadcast.
__global__ __launch_bounds__(64)
void gemm_kernel(const float* __restrict__ phi_im,
                 const float* __restrict__ phi_cli,
                 const float* __restrict__ inv_im,
                 const float* __restrict__ inv_cli,
                 const int* __restrict__ cnt,
                 const int* __restrict__ lists,
                 float* __restrict__ out,
                 unsigned long long* __restrict__ packed) {
    __shared__ float As[1024];
    __shared__ float Bs[1024];
    __shared__ int rIA[32];
    __shared__ int rIB[32];

    // ---- device-side scheduler: map 1D block id -> (z, pair, tile) ----
    const int n0 = cnt[0], n1 = cnt[1], n2 = cnt[2];
    const int ta = (n0 + 31) >> 5, tb = (n1 + 31) >> 5, tc = (n2 + 31) >> 5;
    const int T0 = ta * tb, T1 = ta * tc, T2 = tb * tc;
    const int tot3 = T0 + T1 + T2;
    int bid = blockIdx.x;
    if (bid >= 2 * tot3) return;
    int z = 0;
    if (bid >= tot3) { z = 1; bid -= tot3; }
    int p, gx, nA, nB;
    const int *lA, *lB;
    if (bid < T0)           { p = 0; gx = tb; nA = n0; nB = n1; lA = lists;        lB = lists + 2048; }
    else if (bid < T0 + T1) { bid -= T0;      p = 1; gx = tc; nA = n0; nB = n2; lA = lists;        lB = lists + 4096; }
    else                    { bid -= T0 + T1; p = 2; gx = tc; nA = n1; nB = n2; lA = lists + 2048; lB = lists + 4096; }
    const int by = (int)((unsigned)bid / (unsigned)gx);
    const int bx = (int)((unsigned)bid % (unsigned)gx);
    const int i0 = by * 32, j0 = bx * 32;
    const int pz = z * 3 + p;

    const float* __restrict__ X = z ? phi_cli : phi_im;
    const float* __restrict__ inv = z ? inv_cli : inv_im;
    const int K = z ? D_CLI : D_IM;

    const int tid = threadIdx.x;
    const int ty = tid >> 3;   // 0..7 (rows)
    const int tx = tid & 7;    // 0..7 (cols)

    if (tid < 32) {
        rIA[tid] = lA[min(i0 + tid, nA - 1)];
        rIB[tid] = lB[min(j0 + tid, nB - 1)];
    }
    __syncthreads();

    // staging geometry: idx = 64*l + tid; row = idx>>3; kq = idx&7 (16B chunk)
    const int kq = tid & 7;
    int ra[4], rb[4], stoff[4];
    #pragma unroll
    for (int l = 0; l < 4; l++) {
        int row = 8 * l + (tid >> 3);
        ra[l] = rIA[row];
        rb[l] = rIB[row];
        stoff[l] = row * 32 + ((kq ^ (row >> 2)) << 2);
    }

    float acc[4][4];
    #pragma unroll
    for (int r = 0; r < 4; r++)
        #pragma unroll
        for (int c = 0; c < 4; c++) acc[r][c] = 0.0f;

    // prefetch kk = 0
    float4 fa[4], fb[4];
    #pragma unroll
    for (int l = 0; l < 4; l++) {
        fa[l] = *(const float4*)(X + (size_t)ra[l] * K + (kq << 2));
        fb[l] = *(const float4*)(X + (size_t)rb[l] * K + (kq << 2));
    }

    for (int kk = 0; kk < K; kk += 32) {
        __syncthreads();
        #pragma unroll
        for (int l = 0; l < 4; l++) {
            *(float4*)&As[stoff[l]] = fa[l];
            *(float4*)&Bs[stoff[l]] = fb[l];
        }
        __syncthreads();
        if (kk + 32 < K) {
            #pragma unroll
            for (int l = 0; l < 4; l++) {
                fa[l] = *(const float4*)(X + (size_t)ra[l] * K + kk + 32 + (kq << 2));
                fb[l] = *(const float4*)(X + (size_t)rb[l] * K + kk + 32 + (kq << 2));
            }
        }
        #pragma unroll
        for (int kc = 0; kc < 8; kc++) {
            const int sa = (kc ^ ty) << 2;
            const int sb = (kc ^ tx) << 2;
            float4 a[4], b[4];
            #pragma unroll
            for (int r = 0; r < 4; r++) a[r] = *(const float4*)&As[(ty * 4 + r) * 32 + sa];
            #pragma unroll
            for (int c = 0; c < 4; c++) b[c] = *(const float4*)&Bs[(tx * 4 + c) * 32 + sb];
            #pragma unroll
            for (int r = 0; r < 4; r++)
                #pragma unroll
                for (int c = 0; c < 4; c++) {
                    acc[r][c] = fmaf(a[r].x, b[c].x, acc[r][c]);
                    acc[r][c] = fmaf(a[r].y, b[c].y, acc[r][c]);
                    acc[r][c] = fmaf(a[r].z, b[c].z, acc[r][c]);
                    acc[r][c] = fmaf(a[r].w, b[c].w, acc[r][c]);
                }
        }
    }

    // ---- epilogue: every computed entry is valid (in-bounds) ----
    int oi[4], oj[4];
    float ivA[4], ivB[4];
    bool vr[4], vc[4];
    #pragma unroll
    for (int e = 0; e < 4; e++) {
        int li = ty * 4 + e, lj = tx * 4 + e;
        vr[e] = (i0 + li) < nA;
        vc[e] = (j0 + lj) < nB;
        oi[e] = rIA[li];
        oj[e] = rIB[lj];
        ivA[e] = inv[oi[e]];
        ivB[e] = inv[oj[e]];
    }

    unsigned long long best = 0xFFFFFFFFFFFFFFFFULL;
    float* outm = out + (size_t)pz * NN;
    #pragma unroll
    for (int r = 0; r < 4; r++) {
        if (!vr[r]) continue;
        float* orow = outm + (size_t)oi[r] * NROW;
        #pragma unroll
        for (int c = 0; c < 4; c++) {
            if (!vc[c]) continue;
            float sv = acc[r][c] * (ivA[r] * ivB[c]);
            orow[oj[c]] = sv;
            unsigned long long pk = ((unsigned long long)enc_f32(sv) << 32) |
                                    (unsigned int)(oi[r] * NROW + oj[c]);
            if (pk < best) best = pk;
        }
    }

    // wave argmin reduce (single wave per block)
    #pragma unroll
    for (int off = 32; off > 0; off >>= 1) {
        unsigned long long o = __shfl_down(best, off, 64);
        if (o < best) best = o;
    }
    if (tid == 0 && best != 0xFFFFFFFFFFFFFFFFULL) atomicMin(&packed[pz], best);
}

__global__ void finalize_kernel(const unsigned long long* __restrict__ packed,
                                float* __restrict__ out) {
    int p = threadIdx.x;
    if (p < 6) {
        unsigned long long pk = packed[p];
        float v;
        unsigned int flat;
        if (pk == 0xFFFFFFFFFFFFFFFFULL) {
            v = __builtin_huge_valf();
            flat = 0u;
        } else {
            unsigned int key = (unsigned int)(pk >> 32);
            flat = (unsigned int)pk;
            unsigned int bits = (key & 0x80000000u) ? (key ^ 0x80000000u) : ~key;
            v = __uint_as_float(bits);
        }
        float* mv = out + 6 * NN;
        mv[p] = v;
        float* mi = out + 6 * NN + 6;
        mi[2 * p + 0] = (float)(flat >> 11);
        mi[2 * p + 1] = (float)(flat & 2047u);
    }
}

extern "C" void kernel_launch(void* const* d_in, const int* in_sizes, int n_in,
                              void* d_out, int out_size, void* d_ws, size_t ws_size,
                              hipStream_t stream) {
    const float* phi_im = (const float*)d_in[0];
    const float* phi_cli = (const float*)d_in[1];
    const int* t = (const int*)d_in[2];
    const int* traumatic = (const int*)d_in[3];
    float* out = (float*)d_out;

    char* ws = (char*)d_ws;
    unsigned long long* packed = (unsigned long long*)ws;
    int* cnt = (int*)(ws + 64);
    int* lists = (int*)(ws + 128);
    float* inv_im = (float*)(ws + 24704);
    float* inv_cli = (float*)(ws + 32896);

    init_kernel<<<1, 64, 0, stream>>>(packed, cnt);
    prep_kernel<<<NROW, 256, 0, stream>>>(phi_im, phi_cli, t, traumatic,
                                          inv_im, inv_cli, cnt, lists, out);
    // worst-case tile bound: max(T0+T1+T2) = 1496 per z -> 2992 total
    gemm_kernel<<<3072, 64, 0, stream>>>(phi_im, phi_cli, inv_im, inv_cli,
                                         cnt, lists, out, packed);
    finalize_kernel<<<1, 64, 0, stream>>>(packed, out);
}

// Round 3
// 218.131 us; speedup vs baseline: 1.2440x; 1.0521x over previous
//
#include <hip/hip_runtime.h>
#include <stdint.h>

#define NROW 2048
#define D_IM 1024
#define D_CLI 64
#define EPSF 1e-12f
#define NN ((size_t)NROW * (size_t)NROW)

typedef __attribute__((ext_vector_type(8))) short bf16x8;
typedef __attribute__((ext_vector_type(4))) float f32x4;

// ws layout (bytes) — requires ws_size >= ~23 MB
#define OFF_PACKED   0        // u64[6]
#define OFF_CNT      64       // int[4]
#define OFF_LISTS    128      // int[3*2048]
#define OFF_POS      24704    // int[2048]
#define OFF_COLINFO  32896    // uint[3*2048]
#define OFF_INVIM    57472    // float[2048]
#define OFF_INVCLI   65664    // float[2048]
#define OFF_AH_IM    73856    // ushort[2048*1024] = 4 MB
#define OFF_AL_IM    4268160
#define OFF_AH_CLI   8462464  // ushort[2048*64]
#define OFF_AL_CLI   8724608
#define OFF_SC       8986752  // float, worst ~13.4 MB

__device__ __forceinline__ unsigned int enc_f32(float x) {
    unsigned int u = __float_as_uint(x);
    return (u & 0x80000000u) ? ~u : (u | 0x80000000u);
}
__device__ __forceinline__ unsigned short bf16rn(float x) {
    unsigned int u = __float_as_uint(x);
    return (unsigned short)((u + 0x7FFFu + ((u >> 16) & 1u)) >> 16);
}
__device__ __forceinline__ float bf16tof(unsigned short h) {
    return __uint_as_float(((unsigned int)h) << 16);
}

__global__ void init_kernel(unsigned long long* __restrict__ packed,
                            int* __restrict__ cnt) {
    int t = threadIdx.x;
    if (t < 6) packed[t] = 0xFFFFFFFFFFFFFFFFULL;
    if (t < 4) cnt[t] = 0;
}

// One block per row: norms, bf16 hi/lo split, category/list/pos/colinfo.
__global__ __launch_bounds__(256)
void prep_kernel(const float* __restrict__ phi_im,
                 const float* __restrict__ phi_cli,
                 const int* __restrict__ t,
                 const int* __restrict__ traumatic,
                 float* __restrict__ inv_im,
                 float* __restrict__ inv_cli,
                 int* __restrict__ cnt,
                 int* __restrict__ lists,
                 int* __restrict__ posIn,
                 unsigned int* __restrict__ colinfo,
                 unsigned short* __restrict__ ah_im,
                 unsigned short* __restrict__ al_im,
                 unsigned short* __restrict__ ah_cli,
                 unsigned short* __restrict__ al_cli) {
    __shared__ float sred[256];
    const int r = blockIdx.x;
    const int tid = threadIdx.x;

    // im row: 1024 floats, thread handles 4
    float4 v = ((const float4*)(phi_im + (size_t)r * D_IM))[tid];
    float a[4] = {v.x, v.y, v.z, v.w};
    unsigned short h4[4], l4[4];
    #pragma unroll
    for (int e = 0; e < 4; e++) {
        h4[e] = bf16rn(a[e]);
        l4[e] = bf16rn(a[e] - bf16tof(h4[e]));
    }
    *(ushort4*)(ah_im + (size_t)r * D_IM + tid * 4) =
        make_ushort4(h4[0], h4[1], h4[2], h4[3]);
    *(ushort4*)(al_im + (size_t)r * D_IM + tid * 4) =
        make_ushort4(l4[0], l4[1], l4[2], l4[3]);
    sred[tid] = a[0] * a[0] + a[1] * a[1] + a[2] * a[2] + a[3] * a[3];
    __syncthreads();
    for (int off = 128; off > 0; off >>= 1) {
        if (tid < off) sred[tid] += sred[tid + off];
        __syncthreads();
    }

    // cli row: 64 floats, wave 0 (one scalar each)
    if (tid < 64) {
        float c = phi_cli[(size_t)r * D_CLI + tid];
        unsigned short ch = bf16rn(c);
        unsigned short cl = bf16rn(c - bf16tof(ch));
        ah_cli[(size_t)r * D_CLI + tid] = ch;
        al_cli[(size_t)r * D_CLI + tid] = cl;
        float cs = c * c;
        #pragma unroll
        for (int off = 32; off > 0; off >>= 1) cs += __shfl_down(cs, off, 64);
        if (tid == 0) inv_cli[r] = 1.0f / fmaxf(sqrtf(cs), EPSF);
    }

    if (tid == 0) {
        inv_im[r] = 1.0f / fmaxf(sqrtf(sred[0]), EPSF);
        int t1 = t[2 * r + 1];
        int tr = traumatic[r];
        int cat = (t1 == 1) ? 1 : ((t1 == 2) ? 2 : ((tr == 1) ? 0 : 3));
        unsigned int slot = 0xFFFFFFFFu;
        if (cat < 3) {
            slot = (unsigned int)atomicAdd(&cnt[cat], 1);
            lists[cat * 2048 + slot] = r;
            posIn[r] = (int)slot;
        }
        // col categories per pair: p0->1, p1->2, p2->2
        colinfo[0 * 2048 + r] = (cat == 1) ? slot : 0xFFFFFFFFu;
        colinfo[1 * 2048 + r] = (cat == 2) ? slot : 0xFFFFFFFFu;
        colinfo[2 * 2048 + r] = (cat == 2) ? slot : 0xFFFFFFFFu;
        // cat stored in posIn's high... keep separate: reuse colinfo? store cat:
        // (we pass cat via lists? simplest: dedicated array) -> use posIn only
        // for position; cat goes in cnt-adjacent scratch below.
    }
}

// tiny helper kernel storing cat per row (separate array appended to posIn page)
// -> folded into prep via colinfo pattern: writer derives validity from colinfo
//    for columns; for rows it needs cat explicitly. We store cat in the upper
//    16 bits of posIn instead: posIn[r] = (cat<<24) | slot.

__global__ __launch_bounds__(256)
void cat_kernel(const int* __restrict__ t,
                const int* __restrict__ traumatic,
                int* __restrict__ catArr) {
    int r = blockIdx.x * 256 + threadIdx.x;
    if (r < NROW) {
        int t1 = t[2 * r + 1];
        int tr = traumatic[r];
        catArr[r] = (t1 == 1) ? 1 : ((t1 == 2) ? 2 : ((tr == 1) ? 0 : 3));
    }
}

// Compact gather-GEMM, bf16 MFMA 16x16x32, 3-term split, 64x64 tile,
// single wave per block, no LDS in the K-loop (fragments straight from L2).
__global__ __launch_bounds__(64)
void gemm_kernel(const unsigned short* __restrict__ ah_im,
                 const unsigned short* __restrict__ al_im,
                 const unsigned short* __restrict__ ah_cli,
                 const unsigned short* __restrict__ al_cli,
                 const float* __restrict__ inv_im,
                 const float* __restrict__ inv_cli,
                 const int* __restrict__ cnt,
                 const int* __restrict__ lists,
                 float* __restrict__ Sc) {
    __shared__ float sIA[64], sIB[64];
    __shared__ int sRA[64], sRB[64];

    const int n0 = cnt[0], n1 = cnt[1], n2 = cnt[2];
    const int tA = (n0 + 63) >> 6, tB = (n1 + 63) >> 6, tC = (n2 + 63) >> 6;
    const int T0 = tA * tB, T1 = tA * tC, T2 = tB * tC;
    const int tot = T0 + T1 + T2;
    int bid = blockIdx.x;
    if (bid >= 2 * tot) return;
    int z = 0;
    if (bid >= tot) { z = 1; bid -= tot; }
    const size_t s0 = (size_t)(tA << 6) * (tB << 6);
    const size_t s1 = (size_t)(tA << 6) * (tC << 6);
    const size_t s2 = (size_t)(tB << 6) * (tC << 6);
    size_t scoff = z ? (s0 + s1 + s2) : 0;
    int gx, nA, nB, nBpad;
    const int *lA, *lB;
    if (bid < T0)           { gx = tB; nA = n0; nB = n1; lA = lists;        lB = lists + 2048; nBpad = tB << 6; }
    else if (bid < T0 + T1) { bid -= T0;      scoff += s0;      gx = tC; nA = n0; nB = n2; lA = lists;        lB = lists + 4096; nBpad = tC << 6; }
    else                    { bid -= T0 + T1; scoff += s0 + s1; gx = tC; nA = n1; nB = n2; lA = lists + 2048; lB = lists + 4096; nBpad = tC << 6; }
    const int by = bid / gx, bx = bid % gx;
    const int i0 = by << 6, j0 = bx << 6;

    const unsigned short* ahp = z ? ah_cli : ah_im;
    const unsigned short* alp = z ? al_cli : al_im;
    const float* inv = z ? inv_cli : inv_im;
    const int K = z ? D_CLI : D_IM;
    const int lane = threadIdx.x;

    {
        int ia = lA[min(i0 + lane, nA - 1)];
        int ib = lB[min(j0 + lane, nB - 1)];
        sRA[lane] = ia; sRB[lane] = ib;
        sIA[lane] = inv[ia]; sIB[lane] = inv[ib];
    }
    __syncthreads();

    const int mrow = lane & 15;        // A row / B col / C col
    const int quad = lane >> 4;        // k-octet for A/B, row-quad for C
    const size_t rowb = (size_t)K * 2; // row stride bytes
    size_t offA[4], offB[4];
    #pragma unroll
    for (int mt = 0; mt < 4; mt++) {
        offA[mt] = (size_t)sRA[mt * 16 + mrow] * rowb + quad * 16;
        offB[mt] = (size_t)sRB[mt * 16 + mrow] * rowb + quad * 16;
    }

    f32x4 acc[4][4];
    #pragma unroll
    for (int mt = 0; mt < 4; mt++)
        #pragma unroll
        for (int nt = 0; nt < 4; nt++)
            acc[mt][nt] = (f32x4){0.f, 0.f, 0.f, 0.f};

    const char* pah = (const char*)ahp;
    const char* pal = (const char*)alp;
    const int Kb = K * 2;
    for (int kb = 0; kb < Kb; kb += 64) {   // 32 k per step
        bf16x8 Ah[4], Al[4], Bh[4], Bl[4];
        #pragma unroll
        for (int mt = 0; mt < 4; mt++) {
            Ah[mt] = *(const bf16x8*)(pah + offA[mt] + kb);
            Al[mt] = *(const bf16x8*)(pal + offA[mt] + kb);
            Bh[mt] = *(const bf16x8*)(pah + offB[mt] + kb);
            Bl[mt] = *(const bf16x8*)(pal + offB[mt] + kb);
        }
        #pragma unroll
        for (int mt = 0; mt < 4; mt++)
            #pragma unroll
            for (int nt = 0; nt < 4; nt++) {
                acc[mt][nt] = __builtin_amdgcn_mfma_f32_16x16x32_bf16(
                    Ah[mt], Bh[nt], acc[mt][nt], 0, 0, 0);
                acc[mt][nt] = __builtin_amdgcn_mfma_f32_16x16x32_bf16(
                    Ah[mt], Bl[nt], acc[mt][nt], 0, 0, 0);
                acc[mt][nt] = __builtin_amdgcn_mfma_f32_16x16x32_bf16(
                    Al[mt], Bh[nt], acc[mt][nt], 0, 0, 0);
            }
    }

    // epilogue: scale by inv_i*inv_j, store compact (C/D: col=lane&15,
    // row=quad*4+reg  [m89-verified])
    #pragma unroll
    for (int mt = 0; mt < 4; mt++)
        #pragma unroll
        for (int nt = 0; nt < 4; nt++) {
            const int cloc = nt * 16 + mrow;
            const float ivb = sIB[cloc];
            #pragma unroll
            for (int rr = 0; rr < 4; rr++) {
                const int rloc = mt * 16 + quad * 4 + rr;
                float sv = acc[mt][nt][rr] * (sIA[rloc] * ivb);
                Sc[scoff + (size_t)(i0 + rloc) * nBpad + (j0 + cloc)] = sv;
            }
        }
}

// One block per (row, pz): stream the full 2048-float row exactly once.
__global__ __launch_bounds__(256)
void writer_kernel(const float* __restrict__ Sc,
                   const int* __restrict__ cnt,
                   const int* __restrict__ catArr,
                   const int* __restrict__ posIn,
                   const unsigned int* __restrict__ colinfo,
                   float* __restrict__ out,
                   unsigned long long* __restrict__ packed) {
    const int i = blockIdx.x;
    const int pz = blockIdx.y;
    const int z = pz / 3, p = pz % 3;
    const int tid = threadIdx.x;
    float* orow = out + (size_t)pz * NN + (size_t)i * NROW;

    const int rowcat = (p == 2) ? 1 : 0;
    if (catArr[i] != rowcat) {
        const float4 z4 = make_float4(0.f, 0.f, 0.f, 0.f);
        ((float4*)orow)[tid] = z4;
        ((float4*)orow)[tid + 256] = z4;
        return;
    }

    const int n0 = cnt[0], n1 = cnt[1], n2 = cnt[2];
    const int tA = (n0 + 63) >> 6, tB = (n1 + 63) >> 6, tC = (n2 + 63) >> 6;
    const size_t s0 = (size_t)(tA << 6) * (tB << 6);
    const size_t s1 = (size_t)(tA << 6) * (tC << 6);
    const size_t s2 = (size_t)(tB << 6) * (tC << 6);
    size_t scoff = z ? (s0 + s1 + s2) : 0;
    int nBpad;
    if (p == 0)      { nBpad = tB << 6; }
    else if (p == 1) { scoff += s0;      nBpad = tC << 6; }
    else             { scoff += s0 + s1; nBpad = tC << 6; }

    const float* srow = Sc + scoff + (size_t)(posIn[i] & 0xFFFFFF) * nBpad;
    const uint4* cinfo4 = (const uint4*)(colinfo + p * 2048);

    unsigned long long best = 0xFFFFFFFFFFFFFFFFULL;
    const unsigned int ibase = (unsigned int)i * NROW;
    #pragma unroll
    for (int seg = 0; seg < 2; seg++) {
        const int j4 = tid + seg * 256;
        uint4 inf = cinfo4[j4];
        float4 vv;
        unsigned int ji = (unsigned int)(j4 * 4);
        float v0 = (inf.x != 0xFFFFFFFFu) ? srow[inf.x] : 0.f;
        float v1 = (inf.y != 0xFFFFFFFFu) ? srow[inf.y] : 0.f;
        float v2 = (inf.z != 0xFFFFFFFFu) ? srow[inf.z] : 0.f;
        float v3 = (inf.w != 0xFFFFFFFFu) ? srow[inf.w] : 0.f;
        vv = make_float4(v0, v1, v2, v3);
        if (inf.x != 0xFFFFFFFFu) {
            unsigned long long pk = ((unsigned long long)enc_f32(v0) << 32) | (ibase + ji);
            if (pk < best) best = pk;
        }
        if (inf.y != 0xFFFFFFFFu) {
            unsigned long long pk = ((unsigned long long)enc_f32(v1) << 32) | (ibase + ji + 1);
            if (pk < best) best = pk;
        }
        if (inf.z != 0xFFFFFFFFu) {
            unsigned long long pk = ((unsigned long long)enc_f32(v2) << 32) | (ibase + ji + 2);
            if (pk < best) best = pk;
        }
        if (inf.w != 0xFFFFFFFFu) {
            unsigned long long pk = ((unsigned long long)enc_f32(v3) << 32) | (ibase + ji + 3);
            if (pk < best) best = pk;
        }
        ((float4*)orow)[j4] = vv;
    }

    __shared__ unsigned long long red[256];
    red[tid] = best;
    __syncthreads();
    for (int off = 128; off > 0; off >>= 1) {
        if (tid < off) {
            if (red[tid + off] < red[tid]) red[tid] = red[tid + off];
        }
        __syncthreads();
    }
    if (tid == 0 && red[0] != 0xFFFFFFFFFFFFFFFFULL)
        atomicMin(&packed[pz], red[0]);
}

__global__ void finalize_kernel(const unsigned long long* __restrict__ packed,
                                float* __restrict__ out) {
    int p = threadIdx.x;
    if (p < 6) {
        unsigned long long pk = packed[p];
        float v;
        unsigned int flat;
        if (pk == 0xFFFFFFFFFFFFFFFFULL) {
            v = __builtin_huge_valf();
            flat = 0u;
        } else {
            unsigned int key = (unsigned int)(pk >> 32);
            flat = (unsigned int)pk;
            unsigned int bits = (key & 0x80000000u) ? (key ^ 0x80000000u) : ~key;
            v = __uint_as_float(bits);
        }
        float* mv = out + 6 * NN;
        mv[p] = v;
        float* mi = out + 6 * NN + 6;
        mi[2 * p + 0] = (float)(flat >> 11);
        mi[2 * p + 1] = (float)(flat & 2047u);
    }
}

extern "C" void kernel_launch(void* const* d_in, const int* in_sizes, int n_in,
                              void* d_out, int out_size, void* d_ws, size_t ws_size,
                              hipStream_t stream) {
    const float* phi_im = (const float*)d_in[0];
    const float* phi_cli = (const float*)d_in[1];
    const int* t = (const int*)d_in[2];
    const int* traumatic = (const int*)d_in[3];
    float* out = (float*)d_out;

    char* ws = (char*)d_ws;
    unsigned long long* packed = (unsigned long long*)(ws + OFF_PACKED);
    int* cnt = (int*)(ws + OFF_CNT);
    int* lists = (int*)(ws + OFF_LISTS);
    int* posIn = (int*)(ws + OFF_POS);
    unsigned int* colinfo = (unsigned int*)(ws + OFF_COLINFO);
    float* inv_im = (float*)(ws + OFF_INVIM);
    float* inv_cli = (float*)(ws + OFF_INVCLI);
    unsigned short* ah_im = (unsigned short*)(ws + OFF_AH_IM);
    unsigned short* al_im = (unsigned short*)(ws + OFF_AL_IM);
    unsigned short* ah_cli = (unsigned short*)(ws + OFF_AH_CLI);
    unsigned short* al_cli = (unsigned short*)(ws + OFF_AL_CLI);
    float* Sc = (float*)(ws + OFF_SC);
    // catArr reuses the tail of the lists page spacing: place after colinfo?
    // dedicated: reuse inv pages? keep simple: place at OFF_POS+... use
    // separate region right before INVIM is full; use lists+3*2048 spare?
    // lists page is exactly 3*2048 ints. Use a dedicated slot: the 16 bytes
    // after cnt are free but too small. Use Sc tail? Simplest: carve from
    // the gap between OFF_PACKED structures — allocate catArr inside the
    // colinfo page's predecessor: we instead append catArr after OFF_SC's
    // worst-case end? Risky. Use bytes [OFF_CNT+16, OFF_LISTS): only 48 B.
    // -> carve a real region: posIn page is int[2048]=8 KB; extend by using
    //    upper half of OFF_COLINFO? colinfo needs 24 KB exactly.
    // Final: catArr lives at OFF_AL_CLI + 262144 .. +8 KB (gap before OFF_SC).
    int* catArr = (int*)(ws + OFF_AL_CLI + 262144);  // 8 KB gap ends 8994944<OFF_SC? no:
    // OFF_SC=8986752 == OFF_AL_CLI+262144. Shift Sc usage by 8 KB instead:
    Sc = (float*)(ws + OFF_SC + 8192);

    init_kernel<<<1, 64, 0, stream>>>(packed, cnt);
    cat_kernel<<<8, 256, 0, stream>>>(t, traumatic, catArr);
    prep_kernel<<<NROW, 256, 0, stream>>>(phi_im, phi_cli, t, traumatic,
                                          inv_im, inv_cli, cnt, lists, posIn,
                                          colinfo, ah_im, al_im, ah_cli, al_cli);
    gemm_kernel<<<768, 64, 0, stream>>>(ah_im, al_im, ah_cli, al_cli,
                                        inv_im, inv_cli, cnt, lists, Sc);
    writer_kernel<<<dim3(NROW, 6), 256, 0, stream>>>(Sc, cnt, catArr, posIn,
                                                     colinfo, out, packed);
    finalize_kernel<<<1, 64, 0, stream>>>(packed, out);
}

// Round 5
// 190.960 us; speedup vs baseline: 1.4210x; 1.1423x over previous
//
#include <hip/hip_runtime.h>
#include <stdint.h>

#define NROW 2048
#define D_IM 1024
#define D_CLI 64
#define EPSF 1e-12f
#define NN ((size_t)NROW * (size_t)NROW)

typedef __attribute__((ext_vector_type(8))) short bf16x8;
typedef __attribute__((ext_vector_type(4))) float f32x4;

// ws layout (bytes) — every region end checked against the next start:
//   PACKED   [0,48)
//   CNT      [64,80)
//   CAT      [128,8320)
//   LISTS    [8320,32896)
//   POS      [32896,41088)
//   COLINFO  [41216,65792)    <- was 40960 in R4: overlapped POS by 128 B (the bug)
//   INVIM    [65792,73984)
//   INVCLI   [73984,82176)
//   PIM      [82176,8470784)      2048 rows * 4096 B
//   PCLI     [8470784,8995072)    2048 rows * 256 B
//   SC       [8995072,~22.4MB)    compact scaled S, worst ~13.4 MB
#define OFF_PACKED   0
#define OFF_CNT      64
#define OFF_CAT      128
#define OFF_LISTS    8320
#define OFF_POS      32896
#define OFF_COLINFO  41216
#define OFF_INVIM    65792
#define OFF_INVCLI   73984
#define OFF_PIM      82176
#define OFF_PCLI     8470784
#define OFF_SC       8995072

__device__ __forceinline__ unsigned int enc_f32(float x) {
    unsigned int u = __float_as_uint(x);
    return (u & 0x80000000u) ? ~u : (u | 0x80000000u);
}
__device__ __forceinline__ unsigned short bf16rn(float x) {
    unsigned int u = __float_as_uint(x);
    return (unsigned short)((u + 0x7FFFu + ((u >> 16) & 1u)) >> 16);
}
__device__ __forceinline__ float bf16tof(unsigned short h) {
    return __uint_as_float(((unsigned int)h) << 16);
}

// Single block: categories, deterministic (ascending-row) compaction,
// colinfo, counts, packed-argmin init.
__global__ __launch_bounds__(256)
void scan_kernel(const int* __restrict__ t,
                 const int* __restrict__ traumatic,
                 int* __restrict__ cnt,
                 int* __restrict__ catArr,
                 int* __restrict__ lists,
                 int* __restrict__ posIn,
                 unsigned int* __restrict__ colinfo,
                 unsigned long long* __restrict__ packed) {
    __shared__ unsigned long long ss[256];
    const int tid = threadIdx.x;
    int cats[8];
    unsigned long long mycnt = 0;
    #pragma unroll
    for (int e = 0; e < 8; e++) {
        int r = tid * 8 + e;
        int t1 = t[2 * r + 1];
        int tr = traumatic[r];
        int c = (t1 == 1) ? 1 : ((t1 == 2) ? 2 : ((tr == 1) ? 0 : 3));
        cats[e] = c;
        catArr[r] = c;
        if (c < 3) mycnt += 1ULL << (21 * c);
    }
    ss[tid] = mycnt;
    __syncthreads();
    for (int off = 1; off < 256; off <<= 1) {
        unsigned long long v = (tid >= off) ? ss[tid - off] : 0ULL;
        __syncthreads();
        ss[tid] += v;
        __syncthreads();
    }
    unsigned long long excl = ss[tid] - mycnt;
    unsigned long long tot = ss[255];
    unsigned int loc[3];
    #pragma unroll
    for (int c = 0; c < 3; c++)
        loc[c] = (unsigned int)(excl >> (21 * c)) & 0x1FFFFFu;
    #pragma unroll
    for (int e = 0; e < 8; e++) {
        int r = tid * 8 + e;
        int c = cats[e];
        unsigned int slot = 0xFFFFFFFFu;
        if (c < 3) {
            slot = loc[c]++;
            lists[c * 2048 + slot] = r;
            posIn[r] = (int)slot;
        }
        colinfo[0 * 2048 + r] = (c == 1) ? slot : 0xFFFFFFFFu;
        colinfo[1 * 2048 + r] = (c == 2) ? slot : 0xFFFFFFFFu;
        colinfo[2 * 2048 + r] = (c == 2) ? slot : 0xFFFFFFFFu;
    }
    if (tid == 0) {
        cnt[0] = (int)(tot & 0x1FFFFFu);
        cnt[1] = (int)((tot >> 21) & 0x1FFFFFu);
        cnt[2] = (int)((tot >> 42) & 0x1FFFFFu);
        cnt[3] = 0;
    }
    if (tid < 6) packed[tid] = 0xFFFFFFFFFFFFFFFFULL;
}

// One block per row: norms + packed bf16 hi/lo split.
// Packed layout per row: octet o (8 bf16) at byte o*32: [hi 16B | lo 16B].
__global__ __launch_bounds__(256)
void prep_kernel(const float* __restrict__ phi_im,
                 const float* __restrict__ phi_cli,
                 float* __restrict__ inv_im,
                 float* __restrict__ inv_cli,
                 char* __restrict__ pim,
                 char* __restrict__ pcli) {
    __shared__ float sred[256];
    const int r = blockIdx.x;
    const int tid = threadIdx.x;

    float4 v = ((const float4*)(phi_im + (size_t)r * D_IM))[tid];
    float a[4] = {v.x, v.y, v.z, v.w};
    unsigned short h4[4], l4[4];
    #pragma unroll
    for (int e = 0; e < 4; e++) {
        h4[e] = bf16rn(a[e]);
        l4[e] = bf16rn(a[e] - bf16tof(h4[e]));
    }
    {
        char* rowb = pim + (size_t)r * 4096 + (tid >> 1) * 32 + (tid & 1) * 8;
        *(ushort4*)rowb = make_ushort4(h4[0], h4[1], h4[2], h4[3]);
        *(ushort4*)(rowb + 16) = make_ushort4(l4[0], l4[1], l4[2], l4[3]);
    }
    sred[tid] = a[0] * a[0] + a[1] * a[1] + a[2] * a[2] + a[3] * a[3];
    __syncthreads();
    for (int off = 128; off > 0; off >>= 1) {
        if (tid < off) sred[tid] += sred[tid + off];
        __syncthreads();
    }
    if (tid == 0) inv_im[r] = 1.0f / fmaxf(sqrtf(sred[0]), EPSF);

    if (tid < 16) {
        float4 c = ((const float4*)(phi_cli + (size_t)r * D_CLI))[tid];
        float b[4] = {c.x, c.y, c.z, c.w};
        unsigned short ch[4], cl[4];
        #pragma unroll
        for (int e = 0; e < 4; e++) {
            ch[e] = bf16rn(b[e]);
            cl[e] = bf16rn(b[e] - bf16tof(ch[e]));
        }
        char* rowb = pcli + (size_t)r * 256 + (tid >> 1) * 32 + (tid & 1) * 8;
        *(ushort4*)rowb = make_ushort4(ch[0], ch[1], ch[2], ch[3]);
        *(ushort4*)(rowb + 16) = make_ushort4(cl[0], cl[1], cl[2], cl[3]);
    }
    if (tid < 64) {
        float c = phi_cli[(size_t)r * D_CLI + tid];
        float cs = c * c;
        #pragma unroll
        for (int off = 32; off > 0; off >>= 1) cs += __shfl_down(cs, off, 64);
        if (tid == 0) inv_cli[r] = 1.0f / fmaxf(sqrtf(cs), EPSF);
    }
}

// Compact gather-GEMM: 64x64 tile, 1 wave/block, bf16 MFMA 16x16x32 3-term
// split, fragments direct from L2 with explicit double-buffered prefetch.
#define LOAD_SET(s, AH, AL, BH, BL)                                        \
    {                                                                      \
        const int kb_ = (s) * 128;                                         \
        _Pragma("unroll") for (int mt = 0; mt < 4; mt++) {                 \
            AH[mt] = *(const bf16x8*)(pX + offA[mt] + kb_);                \
            AL[mt] = *(const bf16x8*)(pX + offA[mt] + kb_ + 16);           \
            BH[mt] = *(const bf16x8*)(pX + offB[mt] + kb_);                \
            BL[mt] = *(const bf16x8*)(pX + offB[mt] + kb_ + 16);           \
        }                                                                  \
    }
#define MFMA_SET(AH, AL, BH, BL)                                           \
    _Pragma("unroll") for (int mt = 0; mt < 4; mt++)                       \
        _Pragma("unroll") for (int nt = 0; nt < 4; nt++) {                 \
            acc[mt][nt] = __builtin_amdgcn_mfma_f32_16x16x32_bf16(         \
                AH[mt], BH[nt], acc[mt][nt], 0, 0, 0);                     \
            acc[mt][nt] = __builtin_amdgcn_mfma_f32_16x16x32_bf16(         \
                AH[mt], BL[nt], acc[mt][nt], 0, 0, 0);                     \
            acc[mt][nt] = __builtin_amdgcn_mfma_f32_16x16x32_bf16(         \
                AL[mt], BH[nt], acc[mt][nt], 0, 0, 0);                     \
        }

__global__ __launch_bounds__(64, 2)
void gemm_kernel(const char* __restrict__ pim,
                 const char* __restrict__ pcli,
                 const float* __restrict__ inv_im,
                 const float* __restrict__ inv_cli,
                 const int* __restrict__ cnt,
                 const int* __restrict__ lists,
                 float* __restrict__ Sc) {
    __shared__ float sIA[64], sIB[64];
    __shared__ int sRA[64], sRB[64];

    const int n0 = cnt[0], n1 = cnt[1], n2 = cnt[2];
    const int tA = (n0 + 63) >> 6, tB = (n1 + 63) >> 6, tC = (n2 + 63) >> 6;
    const int T0 = tA * tB, T1 = tA * tC, T2 = tB * tC;
    const int tot = T0 + T1 + T2;
    int bid = blockIdx.x;
    if (bid >= 2 * tot) return;
    int z = 0;
    if (bid >= tot) { z = 1; bid -= tot; }
    const size_t s0 = (size_t)(tA << 6) * (tB << 6);
    const size_t s1 = (size_t)(tA << 6) * (tC << 6);
    const size_t s2 = (size_t)(tB << 6) * (tC << 6);
    size_t scoff = z ? (s0 + s1 + s2) : 0;
    int gx, nA, nB, nBpad;
    const int *lA, *lB;
    if (bid < T0)           { gx = tB; nA = n0; nB = n1; lA = lists;        lB = lists + 2048; nBpad = tB << 6; }
    else if (bid < T0 + T1) { bid -= T0;      scoff += s0;      gx = tC; nA = n0; nB = n2; lA = lists;        lB = lists + 4096; nBpad = tC << 6; }
    else                    { bid -= T0 + T1; scoff += s0 + s1; gx = tC; nA = n1; nB = n2; lA = lists + 2048; lB = lists + 4096; nBpad = tC << 6; }
    const int by = bid / gx, bx = bid % gx;
    const int i0 = by << 6, j0 = bx << 6;

    const char* __restrict__ pX = z ? pcli : pim;
    const float* __restrict__ inv = z ? inv_cli : inv_im;
    const int steps = z ? (D_CLI / 32) : (D_IM / 32);
    const size_t stride = z ? 256 : 4096;
    const int lane = threadIdx.x;

    {
        int ia = lA[min(i0 + lane, nA - 1)];
        int ib = lB[min(j0 + lane, nB - 1)];
        sRA[lane] = ia; sRB[lane] = ib;
        sIA[lane] = inv[ia]; sIB[lane] = inv[ib];
    }
    __syncthreads();

    const int mrow = lane & 15;
    const int quad = lane >> 4;
    size_t offA[4], offB[4];
    #pragma unroll
    for (int mt = 0; mt < 4; mt++) {
        offA[mt] = (size_t)sRA[mt * 16 + mrow] * stride + quad * 32;
        offB[mt] = (size_t)sRB[mt * 16 + mrow] * stride + quad * 32;
    }

    f32x4 acc[4][4];
    #pragma unroll
    for (int mt = 0; mt < 4; mt++)
        #pragma unroll
        for (int nt = 0; nt < 4; nt++)
            acc[mt][nt] = (f32x4){0.f, 0.f, 0.f, 0.f};

    bf16x8 A0h[4], A0l[4], B0h[4], B0l[4];
    bf16x8 A1h[4], A1l[4], B1h[4], B1l[4];
    LOAD_SET(0, A0h, A0l, B0h, B0l);
    for (int s = 0; s < steps; s += 2) {
        if (s + 1 < steps) LOAD_SET(s + 1, A1h, A1l, B1h, B1l);
        MFMA_SET(A0h, A0l, B0h, B0l);
        if (s + 2 < steps) LOAD_SET(s + 2, A0h, A0l, B0h, B0l);
        if (s + 1 < steps) MFMA_SET(A1h, A1l, B1h, B1l);
    }

    // C/D: col = lane&15, row = quad*4+reg  (m89-verified; R3 passed)
    #pragma unroll
    for (int mt = 0; mt < 4; mt++)
        #pragma unroll
        for (int nt = 0; nt < 4; nt++) {
            const int cloc = nt * 16 + mrow;
            const float ivb = sIB[cloc];
            #pragma unroll
            for (int rr = 0; rr < 4; rr++) {
                const int rloc = mt * 16 + quad * 4 + rr;
                float sv = acc[mt][nt][rr] * (sIA[rloc] * ivb);
                Sc[scoff + (size_t)(i0 + rloc) * nBpad + (j0 + cloc)] = sv;
            }
        }
}

// One block per row i; handles all 6 output matrices for that row.
__global__ __launch_bounds__(256)
void writer_kernel(const float* __restrict__ Sc,
                   const int* __restrict__ cnt,
                   const int* __restrict__ catArr,
                   const int* __restrict__ posIn,
                   const unsigned int* __restrict__ colinfo,
                   float* __restrict__ out,
                   unsigned long long* __restrict__ packed) {
    __shared__ unsigned long long red[256];
    const int i = blockIdx.x;
    const int tid = threadIdx.x;
    const int cat = catArr[i];

    const int n0 = cnt[0], n1 = cnt[1], n2 = cnt[2];
    const int tA = (n0 + 63) >> 6, tB = (n1 + 63) >> 6, tC = (n2 + 63) >> 6;
    const size_t s0 = (size_t)(tA << 6) * (tB << 6);
    const size_t s1 = (size_t)(tA << 6) * (tC << 6);
    const size_t s2 = (size_t)(tB << 6) * (tC << 6);

    for (int pz = 0; pz < 6; pz++) {
        const int z = pz / 3, p = pz % 3;
        float* orow = out + (size_t)pz * NN + (size_t)i * NROW;
        const int rowcat = (p == 2) ? 1 : 0;
        if (cat != rowcat) {
            const float4 z4 = make_float4(0.f, 0.f, 0.f, 0.f);
            ((float4*)orow)[tid] = z4;
            ((float4*)orow)[tid + 256] = z4;
            continue;
        }
        size_t scoff = z ? (s0 + s1 + s2) : 0;
        int nBpad;
        if (p == 0)      { nBpad = tB << 6; }
        else if (p == 1) { scoff += s0;      nBpad = tC << 6; }
        else             { scoff += s0 + s1; nBpad = tC << 6; }
        const float* srow = Sc + scoff + (size_t)posIn[i] * nBpad;
        const uint4* cinfo4 = (const uint4*)(colinfo + p * 2048);

        unsigned long long best = 0xFFFFFFFFFFFFFFFFULL;
        const unsigned int ibase = (unsigned int)i * NROW;
        #pragma unroll
        for (int seg = 0; seg < 2; seg++) {
            const int j4 = tid + seg * 256;
            uint4 inf = cinfo4[j4];
            unsigned int ji = (unsigned int)(j4 * 4);
            float v0 = (inf.x != 0xFFFFFFFFu) ? srow[inf.x] : 0.f;
            float v1 = (inf.y != 0xFFFFFFFFu) ? srow[inf.y] : 0.f;
            float v2 = (inf.z != 0xFFFFFFFFu) ? srow[inf.z] : 0.f;
            float v3 = (inf.w != 0xFFFFFFFFu) ? srow[inf.w] : 0.f;
            if (inf.x != 0xFFFFFFFFu) {
                unsigned long long pk = ((unsigned long long)enc_f32(v0) << 32) | (ibase + ji);
                if (pk < best) best = pk;
            }
            if (inf.y != 0xFFFFFFFFu) {
                unsigned long long pk = ((unsigned long long)enc_f32(v1) << 32) | (ibase + ji + 1);
                if (pk < best) best = pk;
            }
            if (inf.z != 0xFFFFFFFFu) {
                unsigned long long pk = ((unsigned long long)enc_f32(v2) << 32) | (ibase + ji + 2);
                if (pk < best) best = pk;
            }
            if (inf.w != 0xFFFFFFFFu) {
                unsigned long long pk = ((unsigned long long)enc_f32(v3) << 32) | (ibase + ji + 3);
                if (pk < best) best = pk;
            }
            ((float4*)orow)[j4] = make_float4(v0, v1, v2, v3);
        }

        red[tid] = best;
        __syncthreads();
        for (int off = 128; off > 0; off >>= 1) {
            if (tid < off) {
                if (red[tid + off] < red[tid]) red[tid] = red[tid + off];
            }
            __syncthreads();
        }
        if (tid == 0 && red[0] != 0xFFFFFFFFFFFFFFFFULL)
            atomicMin(&packed[pz], red[0]);
        __syncthreads();
    }
}

__global__ void finalize_kernel(const unsigned long long* __restrict__ packed,
                                float* __restrict__ out) {
    int p = threadIdx.x;
    if (p < 6) {
        unsigned long long pk = packed[p];
        float v;
        unsigned int flat;
        if (pk == 0xFFFFFFFFFFFFFFFFULL) {
            v = __builtin_huge_valf();
            flat = 0u;
        } else {
            unsigned int key = (unsigned int)(pk >> 32);
            flat = (unsigned int)pk;
            unsigned int bits = (key & 0x80000000u) ? (key ^ 0x80000000u) : ~key;
            v = __uint_as_float(bits);
        }
        float* mv = out + 6 * NN;
        mv[p] = v;
        float* mi = out + 6 * NN + 6;
        mi[2 * p + 0] = (float)(flat >> 11);
        mi[2 * p + 1] = (float)(flat & 2047u);
    }
}

extern "C" void kernel_launch(void* const* d_in, const int* in_sizes, int n_in,
                              void* d_out, int out_size, void* d_ws, size_t ws_size,
                              hipStream_t stream) {
    const float* phi_im = (const float*)d_in[0];
    const float* phi_cli = (const float*)d_in[1];
    const int* t = (const int*)d_in[2];
    const int* traumatic = (const int*)d_in[3];
    float* out = (float*)d_out;

    char* ws = (char*)d_ws;
    unsigned long long* packed = (unsigned long long*)(ws + OFF_PACKED);
    int* cnt = (int*)(ws + OFF_CNT);
    int* catArr = (int*)(ws + OFF_CAT);
    int* lists = (int*)(ws + OFF_LISTS);
    int* posIn = (int*)(ws + OFF_POS);
    unsigned int* colinfo = (unsigned int*)(ws + OFF_COLINFO);
    float* inv_im = (float*)(ws + OFF_INVIM);
    float* inv_cli = (float*)(ws + OFF_INVCLI);
    char* pim = ws + OFF_PIM;
    char* pcli = ws + OFF_PCLI;
    float* Sc = (float*)(ws + OFF_SC);

    scan_kernel<<<1, 256, 0, stream>>>(t, traumatic, cnt, catArr, lists,
                                       posIn, colinfo, packed);
    prep_kernel<<<NROW, 256, 0, stream>>>(phi_im, phi_cli, inv_im, inv_cli,
                                          pim, pcli);
    gemm_kernel<<<800, 64, 0, stream>>>(pim, pcli, inv_im, inv_cli,
                                        cnt, lists, Sc);
    writer_kernel<<<NROW, 256, 0, stream>>>(Sc, cnt, catArr, posIn,
                                            colinfo, out, packed);
    finalize_kernel<<<1, 64, 0, stream>>>(packed, out);
}